// Round 1
// baseline (136.799 us; speedup 1.0000x reference)
//
#include <hip/hip_runtime.h>
#include <math.h>

#define NB 16
#define IMH 288
#define IMW 384
#define NPIX (IMH*IMW)
#define BPB 64      // blocks per batch in reduce
#define TPB 256

// workspace layout (doubles): R[16][9] | t[16][3] | acc[16][27]
#define R_OFF 0
#define T_OFF (NB*9)
#define ACC_OFF (NB*9 + NB*3)
#define WS_DOUBLES (NB*9 + NB*3 + NB*27)

__global__ void init_k(double* ws) {
    int i = threadIdx.x;
    for (int k = i; k < WS_DOUBLES; k += blockDim.x) ws[k] = 0.0;
    __syncthreads();
    if (i < NB) {
        double* R = ws + R_OFF + i * 9;
        R[0] = 1.0; R[4] = 1.0; R[8] = 1.0;
    }
}

__global__ __launch_bounds__(TPB) void reduce_k(const float* __restrict__ x3d,
                                                const float* __restrict__ conf,
                                                const float* __restrict__ Kmat,
                                                double* ws) {
    const int b = blockIdx.x / BPB;
    const int chunk = blockIdx.x % BPB;

    // per-batch pose state (uniform across block)
    const double* Rd = ws + R_OFF + b * 9;
    const double* td = ws + T_OFF + b * 3;
    float R[9], t[3];
    #pragma unroll
    for (int i = 0; i < 9; i++) R[i] = (float)Rd[i];
    #pragma unroll
    for (int i = 0; i < 3; i++) t[i] = (float)td[i];

    const float fx = Kmat[b * 9 + 0];
    const float fy = Kmat[b * 9 + 4];
    const float cx = Kmat[b * 9 + 2];
    const float cy = Kmat[b * 9 + 5];

    // delta = REL_DELTA * sqrt(var_x + var_y) of the fixed pixel grid
    const float delta = (float)(0.1 * sqrt(((double)(IMW*IMW - 1) + (double)(IMH*IMH - 1)) / 12.0));

    double acc[27];
    #pragma unroll
    for (int i = 0; i < 27; i++) acc[i] = 0.0;

    const float* P  = x3d  + (size_t)b * NPIX * 3;
    const float* Wp = conf + (size_t)b * NPIX;

    for (int n = chunk * TPB + threadIdx.x; n < NPIX; n += BPB * TPB) {
        float px = P[3 * n + 0];
        float py = P[3 * n + 1];
        float pz = P[3 * n + 2];
        float w  = Wp[n];

        float Xx = R[0]*px + R[1]*py + R[2]*pz + t[0];
        float Xy = R[3]*px + R[4]*py + R[5]*pz + t[1];
        float Xz = R[6]*px + R[7]*py + R[8]*pz + t[2];
        float z  = fmaxf(Xz, 0.01f);
        float iz = 1.0f / z;

        int v0 = n / IMW;
        int u0 = n - v0 * IMW;
        float rx = fx * Xx * iz + cx - (float)u0;
        float ry = fy * Xy * iz + cy - (float)v0;

        float wrx = w * rx, wry = w * ry;
        float rn = sqrtf(wrx * wrx + wry * wry);
        float rob2 = fminf(1.0f, delta / fmaxf(rn, 1e-8f));
        float s = w * w * rob2;   // wt^2

        float a  = fx * iz;
        float bb = -fx * Xx * iz * iz;
        float c  = fy * iz;
        float d  = -fy * Xy * iz * iz;

        // J rows (2x6): [Jp | -Jp*skew(Xc)]
        float j0[6] = { a, 0.0f, bb,  bb * Xy,        a * Xz - bb * Xx, -a * Xy };
        float j1[6] = { 0.0f, c,  d, -c * Xz + d * Xy, -d * Xx,          c * Xx };

        int k = 0;
        #pragma unroll
        for (int f = 0; f < 6; ++f) {
            #pragma unroll
            for (int g = f; g < 6; ++g) {
                acc[k] += (double)(s * (j0[f] * j0[g] + j1[f] * j1[g]));
                k++;
            }
        }
        #pragma unroll
        for (int f = 0; f < 6; ++f)
            acc[21 + f] += (double)(s * (j0[f] * rx + j1[f] * ry));
    }

    // wave (64-lane) reduction
    #pragma unroll
    for (int i = 0; i < 27; i++) {
        double v = acc[i];
        for (int off = 32; off > 0; off >>= 1) v += __shfl_down(v, off, 64);
        acc[i] = v;
    }

    __shared__ double lds[TPB / 64][27];
    int lane = threadIdx.x & 63;
    int wave = threadIdx.x >> 6;
    if (lane == 0) {
        #pragma unroll
        for (int i = 0; i < 27; i++) lds[wave][i] = acc[i];
    }
    __syncthreads();
    if (threadIdx.x < 27) {
        double v = 0.0;
        #pragma unroll
        for (int wv = 0; wv < TPB / 64; wv++) v += lds[wv][threadIdx.x];
        atomicAdd(ws + ACC_OFF + b * 27 + threadIdx.x, v);
    }
}

__global__ void solve_k(double* ws) {
    int b = threadIdx.x;
    if (b >= NB) return;
    double* acc = ws + ACC_OFF + b * 27;

    double A[6][6], rhs[6];
    int k = 0;
    for (int f = 0; f < 6; f++)
        for (int g = f; g < 6; g++) {
            A[f][g] = acc[k];
            A[g][f] = acc[k];
            k++;
        }
    for (int f = 0; f < 6; f++) rhs[f] = -acc[21 + f];   // dx = -solve(A, JTr)

    double tr = A[0][0] + A[1][1] + A[2][2] + A[3][3] + A[4][4] + A[5][5];
    double damp = 1e-4 * tr / 6.0 + 1e-6;
    for (int f = 0; f < 6; f++) A[f][f] += damp;

    // Cholesky
    double L[6][6];
    for (int i = 0; i < 6; i++) {
        for (int j = 0; j <= i; j++) {
            double sum = A[i][j];
            for (int m = 0; m < j; m++) sum -= L[i][m] * L[j][m];
            if (i == j) L[i][j] = sqrt(fmax(sum, 1e-30));
            else        L[i][j] = sum / L[j][j];
        }
    }
    double y[6];
    for (int i = 0; i < 6; i++) {
        double s = rhs[i];
        for (int m = 0; m < i; m++) s -= L[i][m] * y[m];
        y[i] = s / L[i][i];
    }
    double dx[6];
    for (int i = 5; i >= 0; i--) {
        double s = y[i];
        for (int m = i + 1; m < 6; m++) s -= L[m][i] * dx[m];
        dx[i] = s / L[i][i];
    }

    // t += dx[:3]
    double* t = ws + T_OFF + b * 3;
    t[0] += dx[0]; t[1] += dx[1]; t[2] += dx[2];

    // R = exp_so3(dx[3:]) @ R
    double wx = dx[3], wy = dx[4], wz = dx[5];
    double th = sqrt(wx * wx + wy * wy + wz * wz);
    th = fmax(th, 1e-8);
    double kx = wx / th, ky = wy / th, kz = wz / th;
    double st = sin(th), ct = 1.0 - cos(th);
    // E = I + st*K + ct*(k k^T - I)
    double E[9];
    E[0] = 1.0 + ct * (kx * kx - 1.0);
    E[1] = -st * kz + ct * kx * ky;
    E[2] =  st * ky + ct * kx * kz;
    E[3] =  st * kz + ct * ky * kx;
    E[4] = 1.0 + ct * (ky * ky - 1.0);
    E[5] = -st * kx + ct * ky * kz;
    E[6] = -st * ky + ct * kz * kx;
    E[7] =  st * kx + ct * kz * ky;
    E[8] = 1.0 + ct * (kz * kz - 1.0);

    double* R = ws + R_OFF + b * 9;
    double Rn[9];
    for (int i = 0; i < 3; i++)
        for (int j = 0; j < 3; j++)
            Rn[i * 3 + j] = E[i * 3 + 0] * R[0 * 3 + j] + E[i * 3 + 1] * R[1 * 3 + j] + E[i * 3 + 2] * R[2 * 3 + j];
    for (int i = 0; i < 9; i++) R[i] = Rn[i];

    // clear accumulators for next iteration
    for (int i = 0; i < 27; i++) acc[i] = 0.0;
}

__global__ void final_k(const float* __restrict__ pose, const double* __restrict__ ws, float* out) {
    int lane = threadIdx.x;
    double rot = 0.0, trans = 0.0;
    if (lane < NB) {
        const float* P0 = pose;
        const float* Pb = pose + lane * 16;
        // gt_rel = inv(P0) @ Pb
        double R0t[9];
        for (int i = 0; i < 3; i++)
            for (int j = 0; j < 3; j++) R0t[i * 3 + j] = (double)P0[j * 4 + i];
        double t0i[3];
        for (int i = 0; i < 3; i++)
            t0i[i] = -(R0t[i*3+0] * P0[0*4+3] + R0t[i*3+1] * P0[1*4+3] + R0t[i*3+2] * P0[2*4+3]);
        double Rg[9], tg[3];
        for (int i = 0; i < 3; i++) {
            for (int j = 0; j < 3; j++)
                Rg[i*3+j] = R0t[i*3+0] * Pb[0*4+j] + R0t[i*3+1] * Pb[1*4+j] + R0t[i*3+2] * Pb[2*4+j];
            tg[i] = R0t[i*3+0] * Pb[0*4+3] + R0t[i*3+1] * Pb[1*4+3] + R0t[i*3+2] * Pb[2*4+3] + t0i[i];
        }
        // pred_rel = inv(T0) @ Tb
        const double* Q0  = ws + R_OFF;
        const double* q0t = ws + T_OFF;
        const double* Qb  = ws + R_OFF + lane * 9;
        const double* qbt = ws + T_OFF + lane * 3;
        double Rp0t[9];
        for (int i = 0; i < 3; i++)
            for (int j = 0; j < 3; j++) Rp0t[i * 3 + j] = Q0[j * 3 + i];
        double tp0i[3];
        for (int i = 0; i < 3; i++)
            tp0i[i] = -(Rp0t[i*3+0] * q0t[0] + Rp0t[i*3+1] * q0t[1] + Rp0t[i*3+2] * q0t[2]);
        double Rp[9], tp[3];
        for (int i = 0; i < 3; i++) {
            for (int j = 0; j < 3; j++)
                Rp[i*3+j] = Rp0t[i*3+0] * Qb[0*3+j] + Rp0t[i*3+1] * Qb[1*3+j] + Rp0t[i*3+2] * Qb[2*3+j];
            tp[i] = Rp0t[i*3+0] * qbt[0] + Rp0t[i*3+1] * qbt[1] + Rp0t[i*3+2] * qbt[2] + tp0i[i];
        }
        // trace(Rp^T Rg)
        double trace = 0.0;
        for (int i = 0; i < 3; i++)
            trace += Rp[0*3+i] * Rg[0*3+i] + Rp[1*3+i] * Rg[1*3+i] + Rp[2*3+i] * Rg[2*3+i];
        double cosang = 0.5 * (trace - 1.0);
        double lo = -1.0 + 1e-7, hi = 1.0 - 1e-7;
        cosang = fmin(fmax(cosang, lo), hi);
        rot = acos(cosang);
        double d0 = tp[0] - tg[0], d1 = tp[1] - tg[1], d2 = tp[2] - tg[2];
        trans = sqrt(d0 * d0 + d1 * d1 + d2 * d2);
    }
    for (int off = 8; off > 0; off >>= 1) {
        rot   += __shfl_down(rot, off, 64);
        trans += __shfl_down(trans, off, 64);
    }
    if (lane == 0) {
        rot /= NB; trans /= NB;
        out[0] = (float)(rot + trans);
        out[1] = (float)rot;
        out[2] = (float)trans;
    }
}

extern "C" void kernel_launch(void* const* d_in, const int* in_sizes, int n_in,
                              void* d_out, int out_size, void* d_ws, size_t ws_size,
                              hipStream_t stream) {
    const float* x3d  = (const float*)d_in[0];
    const float* conf = (const float*)d_in[1];
    const float* Kmat = (const float*)d_in[2];
    const float* pose = (const float*)d_in[3];
    float* out = (float*)d_out;
    double* ws = (double*)d_ws;

    hipLaunchKernelGGL(init_k, dim3(1), dim3(256), 0, stream, ws);
    for (int it = 0; it < 5; ++it) {
        hipLaunchKernelGGL(reduce_k, dim3(NB * BPB), dim3(TPB), 0, stream, x3d, conf, Kmat, ws);
        hipLaunchKernelGGL(solve_k, dim3(1), dim3(64), 0, stream, ws);
    }
    hipLaunchKernelGGL(final_k, dim3(1), dim3(64), 0, stream, pose, ws, out);
}